// Round 14
// baseline (2037.325 us; speedup 1.0000x reference)
//
#include <hip/hip_runtime.h>
#include <hip/hip_bf16.h>
#include <math.h>

// ---------------------------------------------------------------------------
// Problem constants
// ---------------------------------------------------------------------------
#define BB   128     // batch
#define TT   1024    // time
#define CC_  512     // channels / variates (N)
#define DD   1024    // model dim
#define DF_  2048    // fc hidden
#define HH   64      // pool hidden
#define INV_SQRT_D 0.03125f   // 1/sqrt(1024)

typedef _Float16 f16;
typedef __attribute__((ext_vector_type(8))) _Float16 f16x8;
typedef __attribute__((ext_vector_type(4))) _Float16 f16x4;
typedef __attribute__((ext_vector_type(2))) _Float16 f16x2;
typedef __attribute__((ext_vector_type(4))) float f32x4;

__device__ __forceinline__ void gload_lds16(const void* g, void* l) {
    // async global->LDS, 16B per lane; LDS dest = wave-uniform base + lane*16
    __builtin_amdgcn_global_load_lds(
        (const __attribute__((address_space(1))) void*)g,
        (__attribute__((address_space(3))) void*)l, 16, 0, 0);
}

// Tile-packed operand layout (half-element index).  For a GEMM operand with
// row dim r (tiles of 128) and contraction dim k (tiles of 32, sub-chunks
// of 8): element (r,k) lives at
//   ((r>>7)*(K>>5) + (k>>5))*4096 + ((k>>3)&3)*1024 + (r&127)*8 + (k&7)
__device__ __forceinline__ long long paddr(long long r, int k, int K) {
    return ((r >> 7) * (long long)(K >> 5) + (k >> 5)) * 4096LL
         + (long long)(((k >> 3) & 3) * 1024 + ((int)(r & 127)) * 8 + (k & 7));
}

// ---------------------------------------------------------------------------
// fp16 MFMA GEMM (fp32 accumulate), 128x128 tile, BK=64, 4 waves,
// single-buffered 2-barrier loop, PACKED operands.
//   C[m,n] = act(alpha*sum_k A[m,k]*B[n,k] + add_c + bias[n])
//   OUT: 0 = fp32 C[M][N] row-major;  1 = packed f16 (r=m, k=n, K=N);
//        2 = packed f16 transposed (r=n, k=m, K=M)
//   ACT: 0 = none, 2 = exact gelu
// M,N multiples of 128; K multiple of 64.
// ---------------------------------------------------------------------------
template <int OUT, int ACT = 0>
__global__ __launch_bounds__(256, 4) void mfma_gemm(
    const f16* __restrict__ A, const f16* __restrict__ B,
    const float* __restrict__ bias, const float* __restrict__ add_c,
    void* __restrict__ C0,
    int M, int N, int K,
    long long sA, long long sB, long long sC, float alpha)
{
    // ---- XCD swizzle on flattened (x,y); identity when nwg % 8 != 0 ----
    const int gx = gridDim.x;
    const int nwg = gx * gridDim.y;
    int lin = blockIdx.y * gx + blockIdx.x;
    if ((nwg & 7) == 0) {
        const int cpx = nwg >> 3;
        lin = (lin & 7) * cpx + (lin >> 3);
    }
    const int bx = lin % gx, by = lin / gx;

    const int bz   = blockIdx.z;
    const int t    = threadIdx.x;
    const int wave = t >> 6, lane = t & 63;
    const int m0 = by * 128, n0 = bx * 128;
    const int wm = (wave >> 1) * 64, wn = (wave & 1) * 64;

    __shared__ __align__(16) f16 As[2][4096];   // 8 KB per sub-tile
    __shared__ __align__(16) f16 Bs[2][4096];

    f32x4 acc[4][4] = {};

    const int wbyte = wave * 1024;               // wave-uniform LDS base
    const long long tA = (long long)bz * sA + (long long)(m0 >> 7) * (K >> 5) * 4096;
    const long long tB = (long long)bz * sB + (long long)(n0 >> 7) * (K >> 5) * 4096;
    const f16* pA = A + tA + t * 8;
    const f16* pB = B + tB + t * 8;

    const int q   = lane >> 4;   // k-chunk for fragment reads
    const int r16 = lane & 15;

    for (int k0 = 0; k0 < K; k0 += 64) {
        const long long ko = (long long)(k0 >> 5) * 4096;
        __syncthreads();                       // previous compute done
        gload_lds16(pA + ko,        (char*)(&As[0][0]) + wbyte);
        gload_lds16(pA + ko + 2048, (char*)(&As[0][0]) + wbyte + 4096);
        gload_lds16(pA + ko + 4096, (char*)(&As[1][0]) + wbyte);
        gload_lds16(pA + ko + 6144, (char*)(&As[1][0]) + wbyte + 4096);
        gload_lds16(pB + ko,        (char*)(&Bs[0][0]) + wbyte);
        gload_lds16(pB + ko + 2048, (char*)(&Bs[0][0]) + wbyte + 4096);
        gload_lds16(pB + ko + 4096, (char*)(&Bs[1][0]) + wbyte);
        gload_lds16(pB + ko + 6144, (char*)(&Bs[1][0]) + wbyte + 4096);
        __syncthreads();                       // drains vmcnt: tiles ready

        #pragma unroll
        for (int s = 0; s < 2; ++s) {
            const f16x8* AV = (const f16x8*)(&As[s][0]);
            const f16x8* BV = (const f16x8*)(&Bs[s][0]);
            f16x8 bfr[4];
            #pragma unroll
            for (int j = 0; j < 4; ++j)
                bfr[j] = BV[q * 128 + wn + j * 16 + r16];
            __builtin_amdgcn_s_setprio(1);
            #pragma unroll
            for (int i = 0; i < 4; ++i) {
                const f16x8 a = AV[q * 128 + wm + i * 16 + r16];
                #pragma unroll
                for (int j = 0; j < 4; ++j)
                    acc[i][j] = __builtin_amdgcn_mfma_f32_16x16x32_f16(
                        a, bfr[j], acc[i][j], 0, 0, 0);
            }
            __builtin_amdgcn_s_setprio(0);
        }
    }

    // epilogue: C/D layout col = lane&15, row = (lane>>4)*4 + r
    const float cadd = add_c ? add_c[0] : 0.0f;
    const int col = lane & 15;
    const int rb  = (lane >> 4) * 4;
    #pragma unroll
    for (int j = 0; j < 4; ++j) {
        const int n = n0 + wn + j * 16 + col;
        const float bv = bias ? bias[n] : 0.0f;
        #pragma unroll
        for (int i = 0; i < 4; ++i) {
            const int m = m0 + wm + i * 16 + rb;
            f32x4 v = acc[i][j];
            #pragma unroll
            for (int r = 0; r < 4; ++r) {
                v[r] = v[r] * alpha + cadd + bv;
                if constexpr (ACT == 2)
                    v[r] = 0.5f * v[r] * (1.0f + erff(v[r] * 0.70710678118654752f));
            }
            if constexpr (OUT == 0) {
                float* C = (float*)C0 + (long long)bz * sC;
                #pragma unroll
                for (int r = 0; r < 4; ++r) C[(long long)(m + r) * N + n] = v[r];
            } else if constexpr (OUT == 1) {
                // packed: (r=m+r, k=n), K=N
                f16* C = (f16*)C0 + (long long)bz * sC;
                #pragma unroll
                for (int r = 0; r < 4; ++r)
                    C[paddr(m + r, n, N)] = (f16)v[r];
            } else {
                // packed transposed: (r=n, k=m..m+3), K=M;  m%8 in {0,4}
                f16* C = (f16*)C0 + (long long)bz * sC;
                f16 p[4];
                #pragma unroll
                for (int r = 0; r < 4; ++r) p[r] = (f16)v[r];
                *reinterpret_cast<f16x4*>(&C[paddr(n, m, M)]) =
                    *reinterpret_cast<f16x4*>(p);
            }
        }
    }
}

// ---------------------------------------------------------------------------
// fp32 [R][Cc] -> packed fp16, output rows = Cc-dim, k = original row (len R)
// ---------------------------------------------------------------------------
__global__ __launch_bounds__(256) void transpose_h_kernel(
    const float* __restrict__ in, f16* __restrict__ o,
    int R, int Cc, long long sIn, long long sOut)
{
    const int b = blockIdx.z;
    in += (long long)b * sIn; o += (long long)b * sOut;
    __shared__ float tile[32][33];
    const int c0 = blockIdx.x * 32, r0 = blockIdx.y * 32;
    const int tx = threadIdx.x & 31, ty = threadIdx.x >> 5;   // 32 x 8
    #pragma unroll
    for (int i = 0; i < 32; i += 8)
        tile[ty + i][tx] = in[(long long)(r0 + ty + i) * Cc + (c0 + tx)];
    __syncthreads();
    #pragma unroll
    for (int i = 0; i < 32; i += 8)
        o[paddr(c0 + ty + i, r0 + tx, R)] = (f16)tile[tx][ty + i];
}

// fp32 [R][1024] -> packed fp16 (K=1024)
__global__ __launch_bounds__(256) void cvt_h_kernel(
    const float* __restrict__ in, f16* __restrict__ o, long long n)
{
    const long long i = ((long long)blockIdx.x * 256 + threadIdx.x) * 4;
    if (i >= n) return;
    const float4 v = *reinterpret_cast<const float4*>(in + i);
    f16 p[4] = {(f16)v.x, (f16)v.y, (f16)v.z, (f16)v.w};
    const long long r = i >> 10;
    const int k = (int)(i & 1023);
    *reinterpret_cast<f16x4*>(&o[paddr(r, k, 1024)]) = *reinterpret_cast<f16x4*>(p);
}

// zero-fill f16 buffer (n halves, multiple of 2048)
__global__ __launch_bounds__(256) void zero_h_kernel(f16* __restrict__ p, long long n)
{
    const long long i = ((long long)blockIdx.x * 256 + threadIdx.x) * 8;
    if (i >= n) return;
    f16x8 z = {};
    *reinterpret_cast<f16x8*>(p + i) = z;
}

// bias pad: out[0..63]=in, out[64..127]=0
__global__ __launch_bounds__(128) void pad_bias_kernel(
    const float* __restrict__ in, float* __restrict__ o)
{
    const int i = threadIdx.x;
    o[i] = (i < HH) ? in[i] : 0.0f;
}

// ---------------------------------------------------------------------------
// LayerNorm over D=1024 on PACKED f16 (K=1024), in place. One block per row.
// ---------------------------------------------------------------------------
__global__ __launch_bounds__(256) void layernorm_p_kernel(
    f16* __restrict__ x, const float* __restrict__ g, const float* __restrict__ b)
{
    const long long row = blockIdx.x;
    const int t = threadIdx.x;
    const long long a = paddr(row, 4 * t, 1024);
    f16x4 v4 = *reinterpret_cast<const f16x4*>(&x[a]);
    float v0 = (float)v4[0], v1 = (float)v4[1], v2 = (float)v4[2], v3 = (float)v4[3];

    __shared__ float red[4];
    float s = v0 + v1 + v2 + v3;
    #pragma unroll
    for (int off = 32; off; off >>= 1) s += __shfl_down(s, off);
    if ((t & 63) == 0) red[t >> 6] = s;
    __syncthreads();
    const float mean = (red[0] + red[1] + red[2] + red[3]) * (1.0f / DD);
    __syncthreads();

    const float d0 = v0 - mean, d1 = v1 - mean, d2 = v2 - mean, d3 = v3 - mean;
    float s2 = d0 * d0 + d1 * d1 + d2 * d2 + d3 * d3;
    #pragma unroll
    for (int off = 32; off; off >>= 1) s2 += __shfl_down(s2, off);
    if ((t & 63) == 0) red[t >> 6] = s2;
    __syncthreads();
    const float var = (red[0] + red[1] + red[2] + red[3]) * (1.0f / DD);
    const float rs = rsqrtf(var + 1e-5f);

    const float4 gg = reinterpret_cast<const float4*>(g)[t];
    const float4 bb = reinterpret_cast<const float4*>(b)[t];
    f16 p[4];
    p[0] = (f16)(d0 * rs * gg.x + bb.x);
    p[1] = (f16)(d1 * rs * gg.y + bb.y);
    p[2] = (f16)(d2 * rs * gg.z + bb.z);
    p[3] = (f16)(d3 * rs * gg.w + bb.w);
    *reinterpret_cast<f16x4*>(&x[a]) = *reinterpret_cast<f16x4*>(p);
}

// ---------------------------------------------------------------------------
// Row softmax over 512 cols, fp32 in -> packed fp16 (K=512)
// ---------------------------------------------------------------------------
__global__ __launch_bounds__(256) void softmax512_h_kernel(
    const float* __restrict__ x, f16* __restrict__ o)
{
    const long long row = blockIdx.x;
    const float2 v = reinterpret_cast<const float2*>(x + row * 512)[threadIdx.x];
    const int t = threadIdx.x;

    __shared__ float red[4];
    float mx = fmaxf(v.x, v.y);
    #pragma unroll
    for (int off = 32; off; off >>= 1) mx = fmaxf(mx, __shfl_down(mx, off));
    if ((t & 63) == 0) red[t >> 6] = mx;
    __syncthreads();
    mx = fmaxf(fmaxf(red[0], red[1]), fmaxf(red[2], red[3]));
    __syncthreads();

    const float e0 = expf(v.x - mx), e1 = expf(v.y - mx);
    float s = e0 + e1;
    #pragma unroll
    for (int off = 32; off; off >>= 1) s += __shfl_down(s, off);
    if ((t & 63) == 0) red[t >> 6] = s;
    __syncthreads();
    s = red[0] + red[1] + red[2] + red[3];
    const float inv = 1.0f / s;

    f16 p[2] = {(f16)(e0 * inv), (f16)(e1 * inv)};
    *reinterpret_cast<f16x2*>(&o[paddr(row, 2 * t, 512)]) =
        *reinterpret_cast<f16x2*>(p);
}

// fp32 row softmax over 512 in place (pool weights)
__global__ __launch_bounds__(256) void softmax512_kernel(float* __restrict__ x)
{
    const long long row = blockIdx.x;
    float2* xr = reinterpret_cast<float2*>(x + row * 512);
    const int t = threadIdx.x;
    float2 v = xr[t];

    __shared__ float red[4];
    float mx = fmaxf(v.x, v.y);
    #pragma unroll
    for (int off = 32; off; off >>= 1) mx = fmaxf(mx, __shfl_down(mx, off));
    if ((t & 63) == 0) red[t >> 6] = mx;
    __syncthreads();
    mx = fmaxf(fmaxf(red[0], red[1]), fmaxf(red[2], red[3]));
    __syncthreads();

    const float e0 = expf(v.x - mx), e1 = expf(v.y - mx);
    float s = e0 + e1;
    #pragma unroll
    for (int off = 32; off; off >>= 1) s += __shfl_down(s, off);
    if ((t & 63) == 0) red[t >> 6] = s;
    __syncthreads();
    s = red[0] + red[1] + red[2] + red[3];
    const float inv = 1.0f / s;
    xr[t] = make_float2(e0 * inv, e1 * inv);
}

// ---------------------------------------------------------------------------
// fp32 tiled GEMM (kept for the small fc head ops)
// ---------------------------------------------------------------------------
#define BM 64
#define BN 64
#define BK 16

template <int TA, int TB, int ACT>
__global__ __launch_bounds__(256) void gemm_kernel(
    const float* __restrict__ A, const float* __restrict__ B,
    const float* __restrict__ bias, const float* __restrict__ add_const_ptr,
    float* __restrict__ C,
    int M, int N, int K,
    long long strideA, long long strideB, long long strideC,
    float alpha)
{
    const int batch = blockIdx.z;
    A += (long long)batch * strideA;
    B += (long long)batch * strideB;
    C += (long long)batch * strideC;

    __shared__ float As[BK][BM + 4];
    __shared__ float Bs[BK][BN + 4];

    const int t  = threadIdx.x;
    const int tx = t & 15;
    const int ty = t >> 4;
    const int m0 = blockIdx.y * BM;
    const int n0 = blockIdx.x * BN;

    float acc[4][4] = {};

    for (int k0 = 0; k0 < K; k0 += BK) {
        if (TA == 0) {
            const int mm = t >> 2;
            const int kk = (t & 3) * 4;
            const float4 v = *reinterpret_cast<const float4*>(
                &A[(long long)(m0 + mm) * K + (k0 + kk)]);
            As[kk + 0][mm] = v.x; As[kk + 1][mm] = v.y;
            As[kk + 2][mm] = v.z; As[kk + 3][mm] = v.w;
        } else {
            const int kk = t >> 4;
            const int mm = (t & 15) * 4;
            const float4 v = *reinterpret_cast<const float4*>(
                &A[(long long)(k0 + kk) * M + (m0 + mm)]);
            *reinterpret_cast<float4*>(&As[kk][mm]) = v;
        }
        if (TB == 0) {
            const int kk = t >> 4;
            const int nn = (t & 15) * 4;
            const float4 v = *reinterpret_cast<const float4*>(
                &B[(long long)(k0 + kk) * N + (n0 + nn)]);
            *reinterpret_cast<float4*>(&Bs[kk][nn]) = v;
        } else {
            const int nn = t >> 2;
            const int kk = (t & 3) * 4;
            const float4 v = *reinterpret_cast<const float4*>(
                &B[(long long)(n0 + nn) * K + (k0 + kk)]);
            Bs[kk + 0][nn] = v.x; Bs[kk + 1][nn] = v.y;
            Bs[kk + 2][nn] = v.z; Bs[kk + 3][nn] = v.w;
        }
        __syncthreads();

        #pragma unroll
        for (int kk = 0; kk < BK; ++kk) {
            float a[4], b[4];
            #pragma unroll
            for (int i = 0; i < 4; ++i) a[i] = As[kk][ty * 4 + i];
            #pragma unroll
            for (int j = 0; j < 4; ++j) b[j] = Bs[kk][tx * 4 + j];
            #pragma unroll
            for (int i = 0; i < 4; ++i)
                #pragma unroll
                for (int j = 0; j < 4; ++j)
                    acc[i][j] = fmaf(a[i], b[j], acc[i][j]);
        }
        __syncthreads();
    }

    const float cadd = add_const_ptr ? add_const_ptr[0] : 0.0f;
    #pragma unroll
    for (int i = 0; i < 4; ++i) {
        const int m = m0 + ty * 4 + i;
        #pragma unroll
        for (int j = 0; j < 4; ++j) {
            const int n = n0 + tx * 4 + j;
            float v = acc[i][j] * alpha + cadd;
            if (bias) v += bias[n];
            if (ACT == 1) v = (v > 0.0f) ? v : 0.01f * v;
            else if (ACT == 2) v = 0.5f * v * (1.0f + erff(v * 0.70710678118654752f));
            C[(long long)m * N + n] = v;
        }
    }
}

// pool_scores[row] = h[row,:64] . Wp2 + bp2   (h row stride = 128)
__global__ __launch_bounds__(256) void pool_score_kernel(
    const float* __restrict__ h, const float* __restrict__ Wp2,
    const float* __restrict__ bp2, float* __restrict__ out)
{
    const int row  = blockIdx.x * 4 + (threadIdx.x >> 6);
    const int lane = threadIdx.x & 63;
    float v = h[(long long)row * 128 + lane] * Wp2[lane];
    #pragma unroll
    for (int off = 32; off; off >>= 1) v += __shfl_down(v, off);
    if (lane == 0) out[row] = v + bp2[0];
}

// pooled[b,d] = sum_n fused[b,n,d] * w[b,n]   (fused = packed f16, K=1024)
__global__ __launch_bounds__(256) void pooled_kernel(
    const f16* __restrict__ fused, const float* __restrict__ w,
    float* __restrict__ out)
{
    const int b = blockIdx.y;
    const int d = blockIdx.x * 256 + threadIdx.x;
    __shared__ float ws_[CC_];
    for (int i = threadIdx.x; i < CC_; i += 256) ws_[i] = w[(long long)b * CC_ + i];
    __syncthreads();
    const long long dpart = (long long)(d >> 5) * 4096
                          + ((d >> 3) & 3) * 1024 + (d & 7);
    float acc = 0.0f;
    for (int n = 0; n < CC_; ++n) {
        const long long r = (long long)b * CC_ + n;
        const long long addr = ((r >> 7) * 32) * 4096 + dpart + (r & 127) * 8;
        acc = fmaf((float)fused[addr], ws_[n], acc);
    }
    out[(long long)b * DD + d] = acc;
}

// rul[b] = |h2[b,:] . Wf3 + bf3|
__global__ __launch_bounds__(256) void rul_kernel(
    const float* __restrict__ h2, const float* __restrict__ Wf3,
    const float* __restrict__ bf3, float* __restrict__ out)
{
    const int b = blockIdx.x;
    const int t = threadIdx.x;
    float acc = 0.0f;
    for (int k = t; k < DF_; k += 256)
        acc = fmaf(h2[(long long)b * DF_ + k], Wf3[k], acc);
    __shared__ float red[4];
    #pragma unroll
    for (int off = 32; off; off >>= 1) acc += __shfl_down(acc, off);
    if ((t & 63) == 0) red[t >> 6] = acc;
    __syncthreads();
    if (t == 0) out[b] = fabsf(red[0] + red[1] + red[2] + red[3] + bf3[0]);
}

// ---------------------------------------------------------------------------
// Launch
// ---------------------------------------------------------------------------
extern "C" void kernel_launch(void* const* d_in, const int* in_sizes, int n_in,
                              void* d_out, int out_size, void* d_ws, size_t ws_size,
                              hipStream_t stream)
{
    const float* x_enc   = (const float*)d_in[0];
    const float* W_emb   = (const float*)d_in[2];
    const float* b_emb   = (const float*)d_in[3];
    const float* g_s     = (const float*)d_in[4];
    const float* b_s     = (const float*)d_in[5];
    const float* basis   = (const float*)d_in[6];
    const float* Wq      = (const float*)d_in[7];
    const float* bq      = (const float*)d_in[8];
    const float* Wk      = (const float*)d_in[9];
    const float* bk      = (const float*)d_in[10];
    const float* Wv      = (const float*)d_in[11];
    const float* bv      = (const float*)d_in[12];
    const float* age_sc  = (const float*)d_in[13];
    const float* g_f     = (const float*)d_in[14];
    const float* b_f     = (const float*)d_in[15];
    const float* Wp1     = (const float*)d_in[16];
    const float* bp1     = (const float*)d_in[17];
    const float* Wp2     = (const float*)d_in[18];
    const float* bp2     = (const float*)d_in[19];
    const float* Wf1     = (const float*)d_in[20];
    const float* bf1     = (const float*)d_in[21];
    const float* Wf2     = (const float*)d_in[22];
    const float* bf2     = (const float*)d_in[23];
    const float* Wf3     = (const float*)d_in[24];
    const float* bf3     = (const float*)d_in[25];
    float* out = (float*)d_out;
    (void)in_sizes; (void)n_in; (void)out_size; (void)ws_size;

    // ---- workspace layout (MB offsets, liveness-reused; peak < 896 MB) ----
    const unsigned long long MBy = 1048576ULL;
    char* ws = (char*)d_ws;
    f16*  xT     = (f16*)(ws + 0 * MBy);       // packed [B] r=C,K=T  ph1-3
    f16*  Wt     = (f16*)(ws + 128 * MBy);     // packed r=D,K=T/D (transient)
    f16*  Wp1p   = (f16*)(ws + 130 * MBy);     // packed r=128(pad),K=D
    float* bp1p  = (float*)(ws + 131 * MBy);   // padded bias [128]
    f16*  sens   = (f16*)(ws + 256 * MBy);     // packed r=BC,K=D  (LN in place)
    f16*  Qp     = (f16*)(ws + 0 * MBy);       // packed r=BC,K=D (xT dead)
    f16*  Kp     = (f16*)(ws + 384 * MBy);     // packed r=BC,K=D
    f16*  S1T    = (f16*)(ws + 512 * MBy);     // packed [B] r=C,K=C
    f16*  bas    = (f16*)(ws + 576 * MBy);     // packed r=C,K=D
    f16*  S2T    = (f16*)(ws + 640 * MBy);     // packed [B] r=C,K=C
    float* S3    = (float*)(ws + 704 * MBy);   // [B][C][C] fp32
    f16*  attn   = (f16*)(ws + 0 * MBy);       // packed r=BC,K=C (Qp dead)
    f16*  VT     = (f16*)(ws + 384 * MBy);     // packed [B] r=D,K=C (Kp dead)
    f16*  fusedp = (f16*)(ws + 512 * MBy);     // packed r=BC,K=D (S1T/bas dead)
    float* hpool = (float*)(ws + 704 * MBy);   // [BC][128] fp32 (S3 dead)
    float* pscr  = (float*)(ws + 840 * MBy);
    float* pooled= (float*)(ws + 842 * MBy);
    float* h1    = (float*)(ws + 844 * MBy);
    float* h2    = (float*)(ws + 848 * MBy);

    const long long CD  = (long long)CC_ * DD;   // 524288
    const long long CCs = (long long)CC_ * CC_;  // 262144
    const long long DC  = (long long)DD * CC_;
    const dim3 blk(256);

    // 1. x_enc [B][T][C] -> xT packed (rows C, K=T) per batch
    transpose_h_kernel<<<dim3(CC_ / 32, TT / 32, BB), blk, 0, stream>>>(
        x_enc, xT, TT, CC_, (long long)TT * CC_, (long long)CC_ * TT);
    // 2. W_emb [T][D] -> Wt packed (rows D, K=T)
    transpose_h_kernel<<<dim3(DD / 32, TT / 32, 1), blk, 0, stream>>>(
        W_emb, Wt, TT, DD, 0, 0);
    // 3. sensor = xT @ Wt^T + b_emb   -> packed f16
    mfma_gemm<1><<<dim3(DD / 128, CC_ / 128, BB), blk, 0, stream>>>(
        xT, Wt, b_emb, nullptr, sens,
        CC_, DD, TT, (long long)CC_ * TT, 0, CD, 1.0f);
    // 4. LayerNorm(sensor) packed in place
    layernorm_p_kernel<<<BB * CC_, blk, 0, stream>>>(sens, g_s, b_s);
    // 5. Wq -> packed; Q = sensor @ Wq + bq -> packed (K=D)
    transpose_h_kernel<<<dim3(DD / 32, DD / 32, 1), blk, 0, stream>>>(
        Wq, Wt, DD, DD, 0, 0);
    mfma_gemm<1><<<dim3(DD / 128, (BB * CC_) / 128, 1), blk, 0, stream>>>(
        sens, Wt, bq, nullptr, Qp,
        BB * CC_, DD, DD, 0, 0, 0, 1.0f);
    // 6. Wk -> packed; K = sensor @ Wk + bk -> packed
    transpose_h_kernel<<<dim3(DD / 32, DD / 32, 1), blk, 0, stream>>>(
        Wk, Wt, DD, DD, 0, 0);
    mfma_gemm<1><<<dim3(DD / 128, (BB * CC_) / 128, 1), blk, 0, stream>>>(
        sens, Wt, bk, nullptr, Kp,
        BB * CC_, DD, DD, 0, 0, 0, 1.0f);
    // 7. S1T = (Q K^T / 32 + age)^T packed (rows C, K=C) per batch
    mfma_gemm<2><<<dim3(CC_ / 128, CC_ / 128, BB), blk, 0, stream>>>(
        Qp, Kp, nullptr, age_sc, S1T,
        CC_, CC_, DD, CD, CD, CCs, INV_SQRT_D);
    // 8. basis -> packed (rows C, K=D); S2T = (Q basis^T / 32)^T packed
    cvt_h_kernel<<<(CC_ * DD) / 1024, blk, 0, stream>>>(
        basis, bas, (long long)CC_ * DD);
    mfma_gemm<2><<<dim3(CC_ / 128, CC_ / 128, BB), blk, 0, stream>>>(
        Qp, bas, nullptr, nullptr, S2T,
        CC_, CC_, DD, CD, 0, CCs, INV_SQRT_D);
    // 9. S3[n,k] = sum_j S2T[n,j]*S1T[k,j]   (fp32 out)
    mfma_gemm<0><<<dim3(CC_ / 128, CC_ / 128, BB), blk, 0, stream>>>(
        S2T, S1T, nullptr, nullptr, S3,
        CC_, CC_, CC_, CCs, CCs, CCs, 1.0f);
    // 10. attn = softmax(S3) -> packed fp16 (rows flat BC, K=C)
    softmax512_h_kernel<<<BB * CC_, blk, 0, stream>>>(S3, attn);
    // 11. Wv -> packed; VT = (sensor @ Wv + bv)^T packed (rows D, K=C)
    transpose_h_kernel<<<dim3(DD / 32, DD / 32, 1), blk, 0, stream>>>(
        Wv, Wt, DD, DD, 0, 0);
    mfma_gemm<2><<<dim3(DD / 128, CC_ / 128, BB), blk, 0, stream>>>(
        sens, Wt, bv, nullptr, VT,
        CC_, DD, DD, CD, 0, DC, 1.0f);
    // 12. fused = attn @ VT^T / 32 -> packed f16 (rows flat BC, K=D)
    mfma_gemm<1><<<dim3(DD / 128, CC_ / 128, BB), blk, 0, stream>>>(
        attn, VT, nullptr, nullptr, fusedp,
        CC_, DD, CC_, CCs, DC, CD, INV_SQRT_D);
    // 13. LayerNorm(fused) packed in place
    layernorm_p_kernel<<<BB * CC_, blk, 0, stream>>>(fusedp, g_f, b_f);
    // 14. Wp1 pad+pack; bp1 pad; hpool = gelu(fused @ Wp1 + bp1)  (MFMA)
    zero_h_kernel<<<64, blk, 0, stream>>>(Wp1p, 131072);
    transpose_h_kernel<<<dim3(HH / 32, DD / 32, 1), blk, 0, stream>>>(
        Wp1, Wp1p, DD, HH, 0, 0);
    pad_bias_kernel<<<1, 128, 0, stream>>>(bp1, bp1p);
    mfma_gemm<0, 2><<<dim3(1, (BB * CC_) / 128, 1), blk, 0, stream>>>(
        fusedp, Wp1p, bp1p, nullptr, hpool,
        BB * CC_, 128, DD, 0, 0, 0, 1.0f);
    // 15. pool scores + softmax over C
    pool_score_kernel<<<(BB * CC_) / 4, blk, 0, stream>>>(hpool, Wp2, bp2, pscr);
    softmax512_kernel<<<BB, blk, 0, stream>>>(pscr);
    // 16. pooled (reads packed fused)
    pooled_kernel<<<dim3(DD / 256, BB), blk, 0, stream>>>(fusedp, pscr, pooled);
    // 17. fc head
    gemm_kernel<0, 0, 1><<<dim3(DF_ / 64, BB / 64, 1), blk, 0, stream>>>(
        pooled, Wf1, bf1, nullptr, h1, BB, DF_, DD, 0, 0, 0, 1.0f);
    gemm_kernel<0, 0, 0><<<dim3(DF_ / 64, BB / 64, 1), blk, 0, stream>>>(
        h1, Wf2, bf2, nullptr, h2, BB, DF_, DF_, 0, 0, 0, 1.0f);
    rul_kernel<<<BB, blk, 0, stream>>>(h2, Wf3, bf3, out);
}

// Round 15
// 1570.994 us; speedup vs baseline: 1.2968x; 1.2968x over previous
//
#include <hip/hip_runtime.h>
#include <hip/hip_bf16.h>
#include <math.h>

// ---------------------------------------------------------------------------
// Problem constants
// ---------------------------------------------------------------------------
#define BB   128     // batch
#define TT   1024    // time
#define CC_  512     // channels / variates (N)
#define DD   1024    // model dim
#define DF_  2048    // fc hidden
#define HH   64      // pool hidden
#define INV_SQRT_D 0.03125f   // 1/sqrt(1024)

typedef _Float16 f16;
typedef __attribute__((ext_vector_type(8))) _Float16 f16x8;
typedef __attribute__((ext_vector_type(4))) _Float16 f16x4;
typedef __attribute__((ext_vector_type(2))) _Float16 f16x2;
typedef __attribute__((ext_vector_type(4))) float f32x4;

__device__ __forceinline__ void gload_lds16(const void* g, void* l) {
    // async global->LDS, 16B per lane; LDS dest = wave-uniform base + lane*16
    __builtin_amdgcn_global_load_lds(
        (const __attribute__((address_space(1))) void*)g,
        (__attribute__((address_space(3))) void*)l, 16, 0, 0);
}

// Tile-packed operand layout (half-element index).  For a GEMM operand with
// row dim r (tiles of 128) and contraction dim k (tiles of 32, sub-chunks
// of 8): element (r,k) lives at
//   ((r>>7)*(K>>5) + (k>>5))*4096 + ((k>>3)&3)*1024 + (r&127)*8 + (k&7)
__device__ __forceinline__ long long paddr(long long r, int k, int K) {
    return ((r >> 7) * (long long)(K >> 5) + (k >> 5)) * 4096LL
         + (long long)(((k >> 3) & 3) * 1024 + ((int)(r & 127)) * 8 + (k & 7));
}

// ---------------------------------------------------------------------------
// fp16 MFMA GEMM (fp32 accumulate), 128x128 tile, BK=64, 4 waves,
// single-buffered 2-barrier loop, PACKED operands.
//   C[m,n] = act(alpha*sum_k A[m,k]*B[n,k] + add_c + bias[n])
//   OUT: 0 = fp32 C[M][N] row-major;  1 = packed f16 (r=m, k=n, K=N);
//        2 = packed f16 transposed (r=n, k=m, K=M)
//   ACT: 0 = none, 2 = exact gelu
// M,N multiples of 128; K multiple of 64.
// ---------------------------------------------------------------------------
template <int OUT, int ACT = 0>
__global__ __launch_bounds__(256, 4) void mfma_gemm(
    const f16* __restrict__ A, const f16* __restrict__ B,
    const float* __restrict__ bias, const float* __restrict__ add_c,
    void* __restrict__ C0,
    int M, int N, int K,
    long long sA, long long sB, long long sC, float alpha)
{
    // ---- XCD swizzle on flattened (x,y); identity when nwg % 8 != 0 ----
    const int gx = gridDim.x;
    const int nwg = gx * gridDim.y;
    int lin = blockIdx.y * gx + blockIdx.x;
    if ((nwg & 7) == 0) {
        const int cpx = nwg >> 3;
        lin = (lin & 7) * cpx + (lin >> 3);
    }
    const int bx = lin % gx, by = lin / gx;

    const int bz   = blockIdx.z;
    const int t    = threadIdx.x;
    const int wave = t >> 6, lane = t & 63;
    const int m0 = by * 128, n0 = bx * 128;
    const int wm = (wave >> 1) * 64, wn = (wave & 1) * 64;

    __shared__ __align__(16) f16 As[2][4096];   // 8 KB per sub-tile
    __shared__ __align__(16) f16 Bs[2][4096];

    f32x4 acc[4][4] = {};

    const int wbyte = wave * 1024;               // wave-uniform LDS base
    const long long tA = (long long)bz * sA + (long long)(m0 >> 7) * (K >> 5) * 4096;
    const long long tB = (long long)bz * sB + (long long)(n0 >> 7) * (K >> 5) * 4096;
    const f16* pA = A + tA + t * 8;
    const f16* pB = B + tB + t * 8;

    const int q   = lane >> 4;   // k-chunk for fragment reads
    const int r16 = lane & 15;

    for (int k0 = 0; k0 < K; k0 += 64) {
        const long long ko = (long long)(k0 >> 5) * 4096;
        __syncthreads();                       // previous compute done
        gload_lds16(pA + ko,        (char*)(&As[0][0]) + wbyte);
        gload_lds16(pA + ko + 2048, (char*)(&As[0][0]) + wbyte + 4096);
        gload_lds16(pA + ko + 4096, (char*)(&As[1][0]) + wbyte);
        gload_lds16(pA + ko + 6144, (char*)(&As[1][0]) + wbyte + 4096);
        gload_lds16(pB + ko,        (char*)(&Bs[0][0]) + wbyte);
        gload_lds16(pB + ko + 2048, (char*)(&Bs[0][0]) + wbyte + 4096);
        gload_lds16(pB + ko + 4096, (char*)(&Bs[1][0]) + wbyte);
        gload_lds16(pB + ko + 6144, (char*)(&Bs[1][0]) + wbyte + 4096);
        __syncthreads();                       // drains vmcnt: tiles ready

        #pragma unroll
        for (int s = 0; s < 2; ++s) {
            const f16x8* AV = (const f16x8*)(&As[s][0]);
            const f16x8* BV = (const f16x8*)(&Bs[s][0]);
            f16x8 bfr[4];
            #pragma unroll
            for (int j = 0; j < 4; ++j)
                bfr[j] = BV[q * 128 + wn + j * 16 + r16];
            __builtin_amdgcn_s_setprio(1);
            #pragma unroll
            for (int i = 0; i < 4; ++i) {
                const f16x8 a = AV[q * 128 + wm + i * 16 + r16];
                #pragma unroll
                for (int j = 0; j < 4; ++j)
                    acc[i][j] = __builtin_amdgcn_mfma_f32_16x16x32_f16(
                        a, bfr[j], acc[i][j], 0, 0, 0);
            }
            __builtin_amdgcn_s_setprio(0);
        }
    }

    // epilogue: C/D layout col = lane&15, row = (lane>>4)*4 + r
    const float cadd = add_c ? add_c[0] : 0.0f;
    const int col = lane & 15;
    const int rb  = (lane >> 4) * 4;
    #pragma unroll
    for (int j = 0; j < 4; ++j) {
        const int n = n0 + wn + j * 16 + col;
        const float bv = bias ? bias[n] : 0.0f;
        #pragma unroll
        for (int i = 0; i < 4; ++i) {
            const int m = m0 + wm + i * 16 + rb;
            f32x4 v = acc[i][j];
            #pragma unroll
            for (int r = 0; r < 4; ++r) {
                v[r] = v[r] * alpha + cadd + bv;
                if constexpr (ACT == 2)
                    v[r] = 0.5f * v[r] * (1.0f + erff(v[r] * 0.70710678118654752f));
            }
            if constexpr (OUT == 0) {
                float* C = (float*)C0 + (long long)bz * sC;
                #pragma unroll
                for (int r = 0; r < 4; ++r) C[(long long)(m + r) * N + n] = v[r];
            } else if constexpr (OUT == 1) {
                // packed: (r=m+r, k=n), K=N
                f16* C = (f16*)C0 + (long long)bz * sC;
                #pragma unroll
                for (int r = 0; r < 4; ++r)
                    C[paddr(m + r, n, N)] = (f16)v[r];
            } else {
                // packed transposed: (r=n, k=m..m+3), K=M;  m%8 in {0,4}
                f16* C = (f16*)C0 + (long long)bz * sC;
                f16 p[4];
                #pragma unroll
                for (int r = 0; r < 4; ++r) p[r] = (f16)v[r];
                *reinterpret_cast<f16x4*>(&C[paddr(n, m, M)]) =
                    *reinterpret_cast<f16x4*>(p);
            }
        }
    }
}

// ---------------------------------------------------------------------------
// fp32 [R][Cc] -> packed fp16, output rows = Cc-dim, k = original row (len R)
// ---------------------------------------------------------------------------
__global__ __launch_bounds__(256) void transpose_h_kernel(
    const float* __restrict__ in, f16* __restrict__ o,
    int R, int Cc, long long sIn, long long sOut)
{
    const int b = blockIdx.z;
    in += (long long)b * sIn; o += (long long)b * sOut;
    __shared__ float tile[32][33];
    const int c0 = blockIdx.x * 32, r0 = blockIdx.y * 32;
    const int tx = threadIdx.x & 31, ty = threadIdx.x >> 5;   // 32 x 8
    #pragma unroll
    for (int i = 0; i < 32; i += 8)
        tile[ty + i][tx] = in[(long long)(r0 + ty + i) * Cc + (c0 + tx)];
    __syncthreads();
    #pragma unroll
    for (int i = 0; i < 32; i += 8)
        o[paddr(c0 + ty + i, r0 + tx, R)] = (f16)tile[tx][ty + i];
}

// fp32 [R][1024] -> packed fp16 (K=1024)
__global__ __launch_bounds__(256) void cvt_h_kernel(
    const float* __restrict__ in, f16* __restrict__ o, long long n)
{
    const long long i = ((long long)blockIdx.x * 256 + threadIdx.x) * 4;
    if (i >= n) return;
    const float4 v = *reinterpret_cast<const float4*>(in + i);
    f16 p[4] = {(f16)v.x, (f16)v.y, (f16)v.z, (f16)v.w};
    const long long r = i >> 10;
    const int k = (int)(i & 1023);
    *reinterpret_cast<f16x4*>(&o[paddr(r, k, 1024)]) = *reinterpret_cast<f16x4*>(p);
}

// zero-fill f16 buffer (n halves, multiple of 2048)
__global__ __launch_bounds__(256) void zero_h_kernel(f16* __restrict__ p, long long n)
{
    const long long i = ((long long)blockIdx.x * 256 + threadIdx.x) * 8;
    if (i >= n) return;
    f16x8 z = {};
    *reinterpret_cast<f16x8*>(p + i) = z;
}

// bias pad: out[0..63]=in, out[64..127]=0
__global__ __launch_bounds__(128) void pad_bias_kernel(
    const float* __restrict__ in, float* __restrict__ o)
{
    const int i = threadIdx.x;
    o[i] = (i < HH) ? in[i] : 0.0f;
}

// ---------------------------------------------------------------------------
// LayerNorm over K=1024 on PACKED f16, in place, COALESCED.
// One block = one 128-row group (32 tiles x 4096 halves = 256 KB contiguous).
// Thread t: row r = t&127, q-half h = t>>7; reads f16x8 at
//   tile*4096 + (2h+qq)*1024 + r*8  -> waves access contiguous 1 KB.
// ---------------------------------------------------------------------------
__global__ __launch_bounds__(256) void layernorm_pg_kernel(
    f16* __restrict__ x, const float* __restrict__ g, const float* __restrict__ b)
{
    f16* base = x + (long long)blockIdx.x * 131072;   // 128 rows * 1024 k
    const int t = threadIdx.x;
    const int r = t & 127;
    const int h = t >> 7;

    __shared__ float gs[1024], bs[1024];
    __shared__ float ssum[256], ssq[256];
    for (int i = t; i < 1024; i += 256) { gs[i] = g[i]; bs[i] = b[i]; }

    // pass 1: per-(row,half) accumulate
    float sum = 0.0f, sq = 0.0f;
    for (int tile = 0; tile < 32; ++tile) {
        #pragma unroll
        for (int qq = 0; qq < 2; ++qq) {
            const f16x8 v = *reinterpret_cast<const f16x8*>(
                base + tile * 4096 + (h * 2 + qq) * 1024 + r * 8);
            #pragma unroll
            for (int j = 0; j < 8; ++j) {
                const float f = (float)v[j];
                sum += f; sq += f * f;
            }
        }
    }
    ssum[t] = sum; ssq[t] = sq;
    __syncthreads();
    const float rsum = ssum[r] + ssum[r + 128];
    const float rsq  = ssq[r]  + ssq[r + 128];
    const float mean = rsum * (1.0f / DD);
    const float var  = rsq * (1.0f / DD) - mean * mean;
    const float rs   = rsqrtf(fmaxf(var, 0.0f) + 1e-5f);

    // pass 2: normalize + write (same coalesced pattern; L2-hot re-read)
    for (int tile = 0; tile < 32; ++tile) {
        #pragma unroll
        for (int qq = 0; qq < 2; ++qq) {
            const int q = h * 2 + qq;
            const int kbase = tile * 32 + q * 8;
            f16* p = base + tile * 4096 + q * 1024 + r * 8;
            const f16x8 v = *reinterpret_cast<const f16x8*>(p);
            f16 o[8];
            #pragma unroll
            for (int j = 0; j < 8; ++j)
                o[j] = (f16)(((float)v[j] - mean) * rs * gs[kbase + j] + bs[kbase + j]);
            *reinterpret_cast<f16x8*>(p) = *reinterpret_cast<f16x8*>(o);
        }
    }
}

// ---------------------------------------------------------------------------
// Row softmax over 512 cols, fp32 in -> packed fp16 (K=512)
// ---------------------------------------------------------------------------
__global__ __launch_bounds__(256) void softmax512_h_kernel(
    const float* __restrict__ x, f16* __restrict__ o)
{
    const long long row = blockIdx.x;
    const float2 v = reinterpret_cast<const float2*>(x + row * 512)[threadIdx.x];
    const int t = threadIdx.x;

    __shared__ float red[4];
    float mx = fmaxf(v.x, v.y);
    #pragma unroll
    for (int off = 32; off; off >>= 1) mx = fmaxf(mx, __shfl_down(mx, off));
    if ((t & 63) == 0) red[t >> 6] = mx;
    __syncthreads();
    mx = fmaxf(fmaxf(red[0], red[1]), fmaxf(red[2], red[3]));
    __syncthreads();

    const float e0 = expf(v.x - mx), e1 = expf(v.y - mx);
    float s = e0 + e1;
    #pragma unroll
    for (int off = 32; off; off >>= 1) s += __shfl_down(s, off);
    if ((t & 63) == 0) red[t >> 6] = s;
    __syncthreads();
    s = red[0] + red[1] + red[2] + red[3];
    const float inv = 1.0f / s;

    f16 p[2] = {(f16)(e0 * inv), (f16)(e1 * inv)};
    *reinterpret_cast<f16x2*>(&o[paddr(row, 2 * t, 512)]) =
        *reinterpret_cast<f16x2*>(p);
}

// fp32 row softmax over 512 in place (pool weights)
__global__ __launch_bounds__(256) void softmax512_kernel(float* __restrict__ x)
{
    const long long row = blockIdx.x;
    float2* xr = reinterpret_cast<float2*>(x + row * 512);
    const int t = threadIdx.x;
    float2 v = xr[t];

    __shared__ float red[4];
    float mx = fmaxf(v.x, v.y);
    #pragma unroll
    for (int off = 32; off; off >>= 1) mx = fmaxf(mx, __shfl_down(mx, off));
    if ((t & 63) == 0) red[t >> 6] = mx;
    __syncthreads();
    mx = fmaxf(fmaxf(red[0], red[1]), fmaxf(red[2], red[3]));
    __syncthreads();

    const float e0 = expf(v.x - mx), e1 = expf(v.y - mx);
    float s = e0 + e1;
    #pragma unroll
    for (int off = 32; off; off >>= 1) s += __shfl_down(s, off);
    if ((t & 63) == 0) red[t >> 6] = s;
    __syncthreads();
    s = red[0] + red[1] + red[2] + red[3];
    const float inv = 1.0f / s;
    xr[t] = make_float2(e0 * inv, e1 * inv);
}

// ---------------------------------------------------------------------------
// fp32 tiled GEMM (kept for the small fc head ops)
// ---------------------------------------------------------------------------
#define BM 64
#define BN 64
#define BK 16

template <int TA, int TB, int ACT>
__global__ __launch_bounds__(256) void gemm_kernel(
    const float* __restrict__ A, const float* __restrict__ B,
    const float* __restrict__ bias, const float* __restrict__ add_const_ptr,
    float* __restrict__ C,
    int M, int N, int K,
    long long strideA, long long strideB, long long strideC,
    float alpha)
{
    const int batch = blockIdx.z;
    A += (long long)batch * strideA;
    B += (long long)batch * strideB;
    C += (long long)batch * strideC;

    __shared__ float As[BK][BM + 4];
    __shared__ float Bs[BK][BN + 4];

    const int t  = threadIdx.x;
    const int tx = t & 15;
    const int ty = t >> 4;
    const int m0 = blockIdx.y * BM;
    const int n0 = blockIdx.x * BN;

    float acc[4][4] = {};

    for (int k0 = 0; k0 < K; k0 += BK) {
        if (TA == 0) {
            const int mm = t >> 2;
            const int kk = (t & 3) * 4;
            const float4 v = *reinterpret_cast<const float4*>(
                &A[(long long)(m0 + mm) * K + (k0 + kk)]);
            As[kk + 0][mm] = v.x; As[kk + 1][mm] = v.y;
            As[kk + 2][mm] = v.z; As[kk + 3][mm] = v.w;
        } else {
            const int kk = t >> 4;
            const int mm = (t & 15) * 4;
            const float4 v = *reinterpret_cast<const float4*>(
                &A[(long long)(k0 + kk) * M + (m0 + mm)]);
            *reinterpret_cast<float4*>(&As[kk][mm]) = v;
        }
        if (TB == 0) {
            const int kk = t >> 4;
            const int nn = (t & 15) * 4;
            const float4 v = *reinterpret_cast<const float4*>(
                &B[(long long)(k0 + kk) * N + (n0 + nn)]);
            *reinterpret_cast<float4*>(&Bs[kk][nn]) = v;
        } else {
            const int nn = t >> 2;
            const int kk = (t & 3) * 4;
            const float4 v = *reinterpret_cast<const float4*>(
                &B[(long long)(n0 + nn) * K + (k0 + kk)]);
            Bs[kk + 0][nn] = v.x; Bs[kk + 1][nn] = v.y;
            Bs[kk + 2][nn] = v.z; Bs[kk + 3][nn] = v.w;
        }
        __syncthreads();

        #pragma unroll
        for (int kk = 0; kk < BK; ++kk) {
            float a[4], b[4];
            #pragma unroll
            for (int i = 0; i < 4; ++i) a[i] = As[kk][ty * 4 + i];
            #pragma unroll
            for (int j = 0; j < 4; ++j) b[j] = Bs[kk][tx * 4 + j];
            #pragma unroll
            for (int i = 0; i < 4; ++i)
                #pragma unroll
                for (int j = 0; j < 4; ++j)
                    acc[i][j] = fmaf(a[i], b[j], acc[i][j]);
        }
        __syncthreads();
    }

    const float cadd = add_const_ptr ? add_const_ptr[0] : 0.0f;
    #pragma unroll
    for (int i = 0; i < 4; ++i) {
        const int m = m0 + ty * 4 + i;
        #pragma unroll
        for (int j = 0; j < 4; ++j) {
            const int n = n0 + tx * 4 + j;
            float v = acc[i][j] * alpha + cadd;
            if (bias) v += bias[n];
            if (ACT == 1) v = (v > 0.0f) ? v : 0.01f * v;
            else if (ACT == 2) v = 0.5f * v * (1.0f + erff(v * 0.70710678118654752f));
            C[(long long)m * N + n] = v;
        }
    }
}

// pool_scores[row] = h[row,:64] . Wp2 + bp2   (h row stride = 128)
__global__ __launch_bounds__(256) void pool_score_kernel(
    const float* __restrict__ h, const float* __restrict__ Wp2,
    const float* __restrict__ bp2, float* __restrict__ out)
{
    const int row  = blockIdx.x * 4 + (threadIdx.x >> 6);
    const int lane = threadIdx.x & 63;
    float v = h[(long long)row * 128 + lane] * Wp2[lane];
    #pragma unroll
    for (int off = 32; off; off >>= 1) v += __shfl_down(v, off);
    if (lane == 0) out[row] = v + bp2[0];
}

// pooled[b,d] = sum_n fused[b,n,d] * w[b,n]   (fused = packed f16, K=1024)
__global__ __launch_bounds__(256) void pooled_kernel(
    const f16* __restrict__ fused, const float* __restrict__ w,
    float* __restrict__ out)
{
    const int b = blockIdx.y;
    const int d = blockIdx.x * 256 + threadIdx.x;
    __shared__ float ws_[CC_];
    for (int i = threadIdx.x; i < CC_; i += 256) ws_[i] = w[(long long)b * CC_ + i];
    __syncthreads();
    const long long dpart = (long long)(d >> 5) * 4096
                          + ((d >> 3) & 3) * 1024 + (d & 7);
    float acc = 0.0f;
    for (int n = 0; n < CC_; ++n) {
        const long long r = (long long)b * CC_ + n;
        const long long addr = ((r >> 7) * 32) * 4096 + dpart + (r & 127) * 8;
        acc = fmaf((float)fused[addr], ws_[n], acc);
    }
    out[(long long)b * DD + d] = acc;
}

// rul[b] = |h2[b,:] . Wf3 + bf3|
__global__ __launch_bounds__(256) void rul_kernel(
    const float* __restrict__ h2, const float* __restrict__ Wf3,
    const float* __restrict__ bf3, float* __restrict__ out)
{
    const int b = blockIdx.x;
    const int t = threadIdx.x;
    float acc = 0.0f;
    for (int k = t; k < DF_; k += 256)
        acc = fmaf(h2[(long long)b * DF_ + k], Wf3[k], acc);
    __shared__ float red[4];
    #pragma unroll
    for (int off = 32; off; off >>= 1) acc += __shfl_down(acc, off);
    if ((t & 63) == 0) red[t >> 6] = acc;
    __syncthreads();
    if (t == 0) out[b] = fabsf(red[0] + red[1] + red[2] + red[3] + bf3[0]);
}

// ---------------------------------------------------------------------------
// Launch
// ---------------------------------------------------------------------------
extern "C" void kernel_launch(void* const* d_in, const int* in_sizes, int n_in,
                              void* d_out, int out_size, void* d_ws, size_t ws_size,
                              hipStream_t stream)
{
    const float* x_enc   = (const float*)d_in[0];
    const float* W_emb   = (const float*)d_in[2];
    const float* b_emb   = (const float*)d_in[3];
    const float* g_s     = (const float*)d_in[4];
    const float* b_s     = (const float*)d_in[5];
    const float* basis   = (const float*)d_in[6];
    const float* Wq      = (const float*)d_in[7];
    const float* bq      = (const float*)d_in[8];
    const float* Wk      = (const float*)d_in[9];
    const float* bk      = (const float*)d_in[10];
    const float* Wv      = (const float*)d_in[11];
    const float* bv      = (const float*)d_in[12];
    const float* age_sc  = (const float*)d_in[13];
    const float* g_f     = (const float*)d_in[14];
    const float* b_f     = (const float*)d_in[15];
    const float* Wp1     = (const float*)d_in[16];
    const float* bp1     = (const float*)d_in[17];
    const float* Wp2     = (const float*)d_in[18];
    const float* bp2     = (const float*)d_in[19];
    const float* Wf1     = (const float*)d_in[20];
    const float* bf1     = (const float*)d_in[21];
    const float* Wf2     = (const float*)d_in[22];
    const float* bf2     = (const float*)d_in[23];
    const float* Wf3     = (const float*)d_in[24];
    const float* bf3     = (const float*)d_in[25];
    float* out = (float*)d_out;
    (void)in_sizes; (void)n_in; (void)out_size; (void)ws_size;

    // ---- workspace layout (MB offsets, liveness-reused; peak < 896 MB) ----
    const unsigned long long MBy = 1048576ULL;
    char* ws = (char*)d_ws;
    f16*  xT     = (f16*)(ws + 0 * MBy);       // packed [B] r=C,K=T  ph1-3
    f16*  Wt     = (f16*)(ws + 128 * MBy);     // packed r=D,K=T/D (transient)
    f16*  Wp1p   = (f16*)(ws + 130 * MBy);     // packed r=128(pad),K=D
    float* bp1p  = (float*)(ws + 131 * MBy);   // padded bias [128]
    f16*  sens   = (f16*)(ws + 256 * MBy);     // packed r=BC,K=D  (LN in place)
    f16*  Qp     = (f16*)(ws + 0 * MBy);       // packed r=BC,K=D (xT dead)
    f16*  Kp     = (f16*)(ws + 384 * MBy);     // packed r=BC,K=D
    f16*  S1T    = (f16*)(ws + 512 * MBy);     // packed [B] r=C,K=C
    f16*  bas    = (f16*)(ws + 576 * MBy);     // packed r=C,K=D
    f16*  S2T    = (f16*)(ws + 640 * MBy);     // packed [B] r=C,K=C
    float* S3    = (float*)(ws + 704 * MBy);   // [B][C][C] fp32
    f16*  attn   = (f16*)(ws + 0 * MBy);       // packed r=BC,K=C (Qp dead)
    f16*  VT     = (f16*)(ws + 384 * MBy);     // packed [B] r=D,K=C (Kp dead)
    f16*  fusedp = (f16*)(ws + 512 * MBy);     // packed r=BC,K=D (S1T/bas dead)
    float* hpool = (float*)(ws + 704 * MBy);   // [BC][128] fp32 (S3 dead)
    float* pscr  = (float*)(ws + 840 * MBy);
    float* pooled= (float*)(ws + 842 * MBy);
    float* h1    = (float*)(ws + 844 * MBy);
    float* h2    = (float*)(ws + 848 * MBy);

    const long long CD  = (long long)CC_ * DD;   // 524288
    const long long CCs = (long long)CC_ * CC_;  // 262144
    const long long DC  = (long long)DD * CC_;
    const dim3 blk(256);

    // 1. x_enc [B][T][C] -> xT packed (rows C, K=T) per batch
    transpose_h_kernel<<<dim3(CC_ / 32, TT / 32, BB), blk, 0, stream>>>(
        x_enc, xT, TT, CC_, (long long)TT * CC_, (long long)CC_ * TT);
    // 2. W_emb [T][D] -> Wt packed (rows D, K=T)
    transpose_h_kernel<<<dim3(DD / 32, TT / 32, 1), blk, 0, stream>>>(
        W_emb, Wt, TT, DD, 0, 0);
    // 3. sensor = xT @ Wt^T + b_emb   -> packed f16
    mfma_gemm<1><<<dim3(DD / 128, CC_ / 128, BB), blk, 0, stream>>>(
        xT, Wt, b_emb, nullptr, sens,
        CC_, DD, TT, (long long)CC_ * TT, 0, CD, 1.0f);
    // 4. LayerNorm(sensor) packed in place (coalesced row-group kernel)
    layernorm_pg_kernel<<<(BB * CC_) / 128, blk, 0, stream>>>(sens, g_s, b_s);
    // 5. Wq -> packed; Q = sensor @ Wq + bq -> packed (K=D)
    transpose_h_kernel<<<dim3(DD / 32, DD / 32, 1), blk, 0, stream>>>(
        Wq, Wt, DD, DD, 0, 0);
    mfma_gemm<1><<<dim3(DD / 128, (BB * CC_) / 128, 1), blk, 0, stream>>>(
        sens, Wt, bq, nullptr, Qp,
        BB * CC_, DD, DD, 0, 0, 0, 1.0f);
    // 6. Wk -> packed; K = sensor @ Wk + bk -> packed
    transpose_h_kernel<<<dim3(DD / 32, DD / 32, 1), blk, 0, stream>>>(
        Wk, Wt, DD, DD, 0, 0);
    mfma_gemm<1><<<dim3(DD / 128, (BB * CC_) / 128, 1), blk, 0, stream>>>(
        sens, Wt, bk, nullptr, Kp,
        BB * CC_, DD, DD, 0, 0, 0, 1.0f);
    // 7. S1T = (Q K^T / 32 + age)^T packed (rows C, K=C) per batch
    mfma_gemm<2><<<dim3(CC_ / 128, CC_ / 128, BB), blk, 0, stream>>>(
        Qp, Kp, nullptr, age_sc, S1T,
        CC_, CC_, DD, CD, CD, CCs, INV_SQRT_D);
    // 8. basis -> packed (rows C, K=D); S2T = (Q basis^T / 32)^T packed
    cvt_h_kernel<<<(CC_ * DD) / 1024, blk, 0, stream>>>(
        basis, bas, (long long)CC_ * DD);
    mfma_gemm<2><<<dim3(CC_ / 128, CC_ / 128, BB), blk, 0, stream>>>(
        Qp, bas, nullptr, nullptr, S2T,
        CC_, CC_, DD, CD, 0, CCs, INV_SQRT_D);
    // 9. S3[n,k] = sum_j S2T[n,j]*S1T[k,j]   (fp32 out)
    mfma_gemm<0><<<dim3(CC_ / 128, CC_ / 128, BB), blk, 0, stream>>>(
        S2T, S1T, nullptr, nullptr, S3,
        CC_, CC_, CC_, CCs, CCs, CCs, 1.0f);
    // 10. attn = softmax(S3) -> packed fp16 (rows flat BC, K=C)
    softmax512_h_kernel<<<BB * CC_, blk, 0, stream>>>(S3, attn);
    // 11. Wv -> packed; VT = (sensor @ Wv + bv)^T packed (rows D, K=C)
    transpose_h_kernel<<<dim3(DD / 32, DD / 32, 1), blk, 0, stream>>>(
        Wv, Wt, DD, DD, 0, 0);
    mfma_gemm<2><<<dim3(DD / 128, CC_ / 128, BB), blk, 0, stream>>>(
        sens, Wt, bv, nullptr, VT,
        CC_, DD, DD, CD, 0, DC, 1.0f);
    // 12. fused = attn @ VT^T / 32 -> packed f16 (rows flat BC, K=D)
    mfma_gemm<1><<<dim3(DD / 128, CC_ / 128, BB), blk, 0, stream>>>(
        attn, VT, nullptr, nullptr, fusedp,
        CC_, DD, CC_, CCs, DC, CD, INV_SQRT_D);
    // 13. LayerNorm(fused) packed in place (coalesced row-group kernel)
    layernorm_pg_kernel<<<(BB * CC_) / 128, blk, 0, stream>>>(fusedp, g_f, b_f);
    // 14. Wp1 pad+pack; bp1 pad; hpool = gelu(fused @ Wp1 + bp1)  (MFMA)
    zero_h_kernel<<<64, blk, 0, stream>>>(Wp1p, 131072);
    transpose_h_kernel<<<dim3(HH / 32, DD / 32, 1), blk, 0, stream>>>(
        Wp1, Wp1p, DD, HH, 0, 0);
    pad_bias_kernel<<<1, 128, 0, stream>>>(bp1, bp1p);
    mfma_gemm<0, 2><<<dim3(1, (BB * CC_) / 128, 1), blk, 0, stream>>>(
        fusedp, Wp1p, bp1p, nullptr, hpool,
        BB * CC_, 128, DD, 0, 0, 0, 1.0f);
    // 15. pool scores + softmax over C
    pool_score_kernel<<<(BB * CC_) / 4, blk, 0, stream>>>(hpool, Wp2, bp2, pscr);
    softmax512_kernel<<<BB, blk, 0, stream>>>(pscr);
    // 16. pooled (reads packed fused)
    pooled_kernel<<<dim3(DD / 256, BB), blk, 0, stream>>>(fusedp, pscr, pooled);
    // 17. fc head
    gemm_kernel<0, 0, 1><<<dim3(DF_ / 64, BB / 64, 1), blk, 0, stream>>>(
        pooled, Wf1, bf1, nullptr, h1, BB, DF_, DD, 0, 0, 0, 1.0f);
    gemm_kernel<0, 0, 0><<<dim3(DF_ / 64, BB / 64, 1), blk, 0, stream>>>(
        h1, Wf2, bf2, nullptr, h2, BB, DF_, DF_, 0, 0, 0, 1.0f);
    rul_kernel<<<BB, blk, 0, stream>>>(h2, Wf3, bf3, out);
}